// Round 6
// baseline (227.613 us; speedup 1.0000x reference)
//
#include <hip/hip_runtime.h>
#include <hip/hip_bf16.h>
#include <cstdint>

// Problem: out = x @ (W + scale*B@A)^T + b
//   x[4,2048,2048] -> X[M=8192, K=2048],  W[N=2048, K=2048], b[N],
//   A[R=16, K], B[N, R=16], scale scalar.  ALL I/O IS FLOAT32.
// Pipeline: fused aux (cvt x->bf16, XCD-aligned + LoRA fold), one MFMA GEMM.
// R4: BK=64 + XOR bank swizzle      -> GEMM 88.7 us, 0 conflicts.
// R5: XCD-rectangle block swizzle   -> GEMM 83.4 us, FETCH 139->65.6 MB.
// R6: 32x32x16 MFMA (2382 vs 2075 TF ubench) + producer/consumer L2 align.

typedef __bf16 bf16x8 __attribute__((ext_vector_type(8)));
typedef float floatx16 __attribute__((ext_vector_type(16)));
typedef unsigned short ushort8 __attribute__((ext_vector_type(8)));

#define BM 128
#define BN 128
#define BK 64

__device__ __forceinline__ void gload_lds16(const void* g, void* l) {
    // 16B-per-lane async global->LDS. LDS dest must be wave-uniform base + lane*16.
    __builtin_amdgcn_global_load_lds((__attribute__((address_space(1))) void*)g,
                                     (__attribute__((address_space(3))) void*)l,
                                     16, 0, 0);
}

// fp32 -> bf16 bits, round-to-nearest-even (finite inputs only).
__device__ __forceinline__ unsigned short f2bf_bits(float f) {
    unsigned int u = __float_as_uint(f);
    u += 0x7FFFu + ((u >> 16) & 1u);
    return (unsigned short)(u >> 16);
}

// ---------------------------------------------------------------------------
// Fused aux kernel.
//   blocks [0, 8192):      Xbf = bf16(x), XCD-ALIGNED: block bid writes row
//                          (bid&7)<<10 | bid>>3 so the producer's XCD L2 is
//                          the consumer GEMM block's XCD L2 (R5 rectangle map).
//   blocks [8192, 10240):  Weff = bf16(W + scale*B@A)
// ---------------------------------------------------------------------------
__global__ __launch_bounds__(256)
void aux_kernel(const float* __restrict__ x, unsigned short* __restrict__ Xbf,
                const float* __restrict__ W, const float* __restrict__ A,
                const float* __restrict__ Bm, const float* __restrict__ scale_p,
                unsigned short* __restrict__ Weff)
{
    const int K = 2048, R = 16;
    int bid = blockIdx.x;
    if (bid < 8192) {
        // ---- cvt x -> bf16, one 2048-elem row per block ----
        int row = ((bid & 7) << 10) | (bid >> 3);   // match GEMM XCD rectangles
        size_t i = (size_t)row * 2048 + threadIdx.x * 8;
        float4 a = *reinterpret_cast<const float4*>(x + i);
        float4 b = *reinterpret_cast<const float4*>(x + i + 4);
        ushort8 o;
        o[0] = f2bf_bits(a.x); o[1] = f2bf_bits(a.y);
        o[2] = f2bf_bits(a.z); o[3] = f2bf_bits(a.w);
        o[4] = f2bf_bits(b.x); o[5] = f2bf_bits(b.y);
        o[6] = f2bf_bits(b.z); o[7] = f2bf_bits(b.w);
        *reinterpret_cast<ushort8*>(Xbf + i) = o;
    } else {
        // ---- fold LoRA into W_eff ----
        int t  = (bid - 8192) * 256 + threadIdx.x;
        int n  = t >> 8;
        int k8 = (t & 255) << 3;

        float s = *scale_p;
        float br[16];
#pragma unroll
        for (int r = 0; r < R; ++r)
            br[r] = s * Bm[n * R + r];

        float acc[8] = {0,0,0,0,0,0,0,0};
#pragma unroll
        for (int r = 0; r < R; ++r) {
            const float* ap = A + r * K + k8;
#pragma unroll
            for (int j = 0; j < 8; ++j)
                acc[j] += br[r] * ap[j];
        }

        const float* wp = W + (size_t)n * K + k8;
        ushort8 o;
#pragma unroll
        for (int j = 0; j < 8; ++j)
            o[j] = f2bf_bits(wp[j] + acc[j]);
        *reinterpret_cast<ushort8*>(Weff + (size_t)n * K + k8) = o;
    }
}

// ---------------------------------------------------------------------------
// GEMM: out[M,N] (fp32) = Xbf[M,K] @ Weffbf[N,K]^T + bias (fp32)
// 128x128 tile, BK=64, 4 waves 2x2 (wave tile 64x64 = 2x2 of 32x32 frags),
// v_mfma_f32_32x32x16_bf16, 16 MFMA per barrier, XOR bank swizzle, XCD-
// rectangle 1-D grid swizzle.
// A/B operand layout (32x32x16): elem[m = lane&31][k = (lane>>5)*8 + j].
// C/D layout (m74/m101): col = lane&31, row = (reg&3) + 8*(reg>>2) + 4*(lane>>5).
// ---------------------------------------------------------------------------
__global__ __launch_bounds__(256)
void gemm_bias_kernel(const unsigned short* __restrict__ X,
                      const unsigned short* __restrict__ Wt,
                      const float* __restrict__ bias,
                      float* __restrict__ out)
{
    const int N = 2048, K = 2048;

    __shared__ alignas(16) unsigned short As[BM * BK];   // 16 KB
    __shared__ alignas(16) unsigned short Bs[BN * BK];   // 16 KB

    const int tid  = threadIdx.x;
    const int wave = tid >> 6;
    const int lane = tid & 63;

    // XCD-rectangle swizzle: XCD k owns bm-stripes [8k,8k+8) x all 16 bn.
    const int id  = blockIdx.x;          // 0..1023
    const int xcd = id & 7;
    const int s   = id >> 3;             // 0..127
    const int bm  = ((xcd << 3) | (s & 7)) * BM;
    const int bn  = (s >> 3) * BN;

    // Staging: 64-col rows = 8 slots x 16B; slot s of row r holds global
    // col-group s ^ (r&7)  (XOR bank swizzle via swizzled SOURCE address).
    const int srow  = tid >> 3;                      // 0..31 per round
    const int sslot = tid & 7;
    const int sgcol = (sslot ^ (srow & 7)) << 3;

    const int wm    = (wave >> 1) << 6;  // 0 / 64
    const int wn    = (wave & 1) << 6;   // 0 / 64
    const int mrow  = lane & 31;         // operand row within 32
    const int khalf = lane >> 5;         // 0 / 1

    floatx16 acc[2][2] = {};

    const unsigned short* gA = X  + (size_t)(bm + srow) * K + sgcol;
    const unsigned short* gB = Wt + (size_t)(bn + srow) * K + sgcol;
    unsigned short* lA = As + tid * 8;   // dest: wave-uniform base + lane*16B
    unsigned short* lB = Bs + tid * 8;

    for (int k0 = 0; k0 < K; k0 += BK) {
#pragma unroll
        for (int rd = 0; rd < 4; ++rd)
            gload_lds16(gA + (size_t)(rd * 32) * K + k0, lA + rd * 32 * BK);
#pragma unroll
        for (int rd = 0; rd < 4; ++rd)
            gload_lds16(gB + (size_t)(rd * 32) * K + k0, lB + rd * 32 * BK);
        __syncthreads();

#pragma unroll
        for (int ks = 0; ks < 4; ++ks) {           // 4 k-steps of 16
            // col-group cg = ks*2 + khalf; row&7 == lane&7 for all frag rows.
            const int soff = ((ks * 2 + khalf) ^ (lane & 7)) << 3;
            bf16x8 a0 = *reinterpret_cast<const bf16x8*>(As + (wm +      mrow) * BK + soff);
            bf16x8 a1 = *reinterpret_cast<const bf16x8*>(As + (wm + 32 + mrow) * BK + soff);
            bf16x8 b0 = *reinterpret_cast<const bf16x8*>(Bs + (wn +      mrow) * BK + soff);
            bf16x8 b1 = *reinterpret_cast<const bf16x8*>(Bs + (wn + 32 + mrow) * BK + soff);
            acc[0][0] = __builtin_amdgcn_mfma_f32_32x32x16_bf16(a0, b0, acc[0][0], 0, 0, 0);
            acc[0][1] = __builtin_amdgcn_mfma_f32_32x32x16_bf16(a0, b1, acc[0][1], 0, 0, 0);
            acc[1][0] = __builtin_amdgcn_mfma_f32_32x32x16_bf16(a1, b0, acc[1][0], 0, 0, 0);
            acc[1][1] = __builtin_amdgcn_mfma_f32_32x32x16_bf16(a1, b1, acc[1][1], 0, 0, 0);
        }
        __syncthreads();
    }

    // Epilogue. col = bn+wn+ni*32+mrow; row = bm+wm+mi*32+(reg&3)+8*(reg>>2)+4*khalf.
    float bsv[2];
#pragma unroll
    for (int ni = 0; ni < 2; ++ni)
        bsv[ni] = bias[bn + wn + ni * 32 + mrow];

#pragma unroll
    for (int mi = 0; mi < 2; ++mi) {
#pragma unroll
        for (int reg = 0; reg < 16; ++reg) {
            int row = bm + wm + mi * 32 + (reg & 3) + 8 * (reg >> 2) + 4 * khalf;
            size_t rowoff = (size_t)row * N;
#pragma unroll
            for (int ni = 0; ni < 2; ++ni)
                out[rowoff + bn + wn + ni * 32 + mrow] = acc[mi][ni][reg] + bsv[ni];
        }
    }
}

extern "C" void kernel_launch(void* const* d_in, const int* in_sizes, int n_in,
                              void* d_out, int out_size, void* d_ws, size_t ws_size,
                              hipStream_t stream)
{
    const float* x  = (const float*)d_in[0];
    const float* W  = (const float*)d_in[1];
    const float* b  = (const float*)d_in[2];
    const float* A  = (const float*)d_in[3];
    const float* Bm = (const float*)d_in[4];
    const float* sc = (const float*)d_in[5];
    float* out = (float*)d_out;

    const size_t M = 8192, N = 2048, K = 2048;

    unsigned short* Xbf  = (unsigned short*)d_ws;                 // 32 MB
    unsigned short* Weff = (unsigned short*)d_ws + M * K;         // + 8 MB

    // 1) fused: Xbf = bf16(x) (XCD-aligned rows); Weff = bf16(W + scale*B@A)
    aux_kernel<<<dim3((M * K + N * K) / 8 / 256), dim3(256), 0, stream>>>(
        x, Xbf, W, A, Bm, sc, Weff);

    // 2) out = Xbf @ Weff^T + b  (fp32 out), XCD-swizzled 1-D grid
    gemm_bias_kernel<<<dim3((M / BM) * (N / BN)), dim3(256), 0, stream>>>(
        Xbf, Weff, b, out);
}